// Round 1
// baseline (2873.374 us; speedup 1.0000x reference)
//
#include <hip/hip_runtime.h>
#include <math.h>

// Problem constants (shapes fixed by setup_inputs)
#define NV 4          // videos
#define FPV 64        // frames per video
#define NREC 240      // text records / kept adjacency pairs
#define TT 32         // text sequence length
#define EDIM 300
#define HID 256
#define G4 1024       // 4*HID
#define OC 32
#define NCLS 20
#define IMGF 6272     // OC*14*14
#define FEATD 6784    // IMGF + 2*HID
#define NROW 7680     // NREC*TT
#define IMG_PIX 50176 // 224*224

// ---------------- prep: transpose conv weights to [k][oc] ----------------
__global__ void prep_wT_kernel(const float* __restrict__ cw, float* __restrict__ wT) {
    int idx = blockIdx.x * 256 + threadIdx.x;
    if (idx < 441 * 32) {
        int o = idx & 31, k = idx >> 5;
        wT[idx] = cw[o * 441 + k];
    }
}

// ---------------- prep: Whh[l][d][j][k] -> whhT[l][d][k][hu][g] ----------
__global__ void prep_whhT_kernel(const float* __restrict__ w0,
                                 const float* __restrict__ w1,
                                 float* __restrict__ whhT) {
    int idx = blockIdx.x * 256 + threadIdx.x;  // < 2^20
    int g  = idx & 3;
    int hu = (idx >> 2) & 255;
    int k  = (idx >> 10) & 255;
    int d  = (idx >> 18) & 1;
    int l  = (idx >> 19) & 1;
    const float* W = l ? w1 : w0;
    whhT[idx] = W[((size_t)d * G4 + (g * 256 + hu)) * 256 + k];
}

// ---------------- conv3d (7x7x3, stride 1,2,2, pad 1,3,3) + 8x8 spatial maxpool
// grid: (v*64+f)*14+i blocks; block 256 thr; thread -> (pool col j = t>>4, slot s = t&15)
// each thread computes 4 of the 64 conv pixels in pool cell (i,j), all 32 oc.
__global__ __launch_bounds__(256) void conv_pool_kernel(
    const float* __restrict__ img,   // [256][3][224][224]
    const float* __restrict__ wT,    // [441][32]
    const float* __restrict__ cb,    // [32]
    float* __restrict__ spool)       // [4][32][64][196]
{
    int blk = blockIdx.x;
    int i  = blk % 14;
    int vf = blk / 14;       // v*64+f
    int f  = vf & 63;
    int v  = vf >> 6;
    int t  = threadIdx.x;
    int j  = t >> 4; if (j > 13) j = 13;   // lanes 224..255 duplicate j=13 (never written)
    int s  = t & 15;

    float vmax[32];
#pragma unroll
    for (int o = 0; o < 32; o++) vmax[o] = -3.0e38f;

#pragma unroll 1
    for (int q = 0; q < 4; q++) {
        int p  = (q << 4) | s;          // 0..63 window position
        int dy = p >> 3, dx = p & 7;
        int ybase = 2 * (i * 8 + dy) - 3;
        int xbase = 2 * (j * 8 + dx) - 3;
        float acc[32];
#pragma unroll
        for (int o = 0; o < 32; o++) acc[o] = cb[o];
#pragma unroll 1
        for (int c = 0; c < 3; c++) {
#pragma unroll 1
            for (int kd = 0; kd < 3; kd++) {
                int fz = f + kd - 1;
                if (fz < 0 || fz > 63) continue;   // uniform branch (f,kd uniform)
                const float* base = img + ((size_t)(vf + kd - 1) * 3 + c) * IMG_PIX;
                for (int kh = 0; kh < 7; kh++) {
                    int yy = ybase + kh;
                    bool yok = (unsigned)yy < 224u;
                    const float* row = base + (yok ? yy : 0) * 224;
                    const float* wk = wT + ((c * 3 + kd) * 7 + kh) * 7 * 32;
#pragma unroll
                    for (int kw = 0; kw < 7; kw++) {
                        int xx = xbase + kw;
                        bool ok = yok && ((unsigned)xx < 224u);
                        float xv = row[ok ? xx : 0];
                        xv = ok ? xv : 0.0f;
#pragma unroll
                        for (int o = 0; o < 32; o++)
                            acc[o] = fmaf(xv, wk[kw * 32 + o], acc[o]);  // wk: uniform -> s_load
                    }
                }
            }
        }
#pragma unroll
        for (int o = 0; o < 32; o++) vmax[o] = fmaxf(vmax[o], acc[o]);
    }
    // max-reduce over the 16 slots (16 consecutive lanes)
#pragma unroll
    for (int m = 1; m < 16; m <<= 1) {
#pragma unroll
        for (int o = 0; o < 32; o++)
            vmax[o] = fmaxf(vmax[o], __shfl_xor(vmax[o], m, 64));
    }
    if (s == 0 && (threadIdx.x >> 4) < 14) {
#pragma unroll
        for (int o = 0; o < 32; o++)
            spool[(((size_t)(v * 32 + o)) * 64 + f) * 196 + i * 14 + j] = vmax[o];
    }
}

// ---------------- depth maxpool (window 3, pad 1) + adjacent-frame avg -> feat image cols
__global__ void depth_adj_kernel(const float* __restrict__ spool, float* __restrict__ feat) {
    int idx = blockIdx.x * 256 + threadIdx.x;
    if (idx >= NREC * IMGF) return;
    int col = idx % IMGF;
    int r   = idx / IMGF;
    int o  = col / 196, ij = col % 196;
    int g  = r / 15, jj = r % 15;
    int tt = 16 * g + jj;            // kept adjacency index
    int v  = tt >> 6, f = tt & 63;
    const float* S = spool + ((size_t)(v * 32 + o)) * 64 * 196 + ij;
    // P(f) = max over [f-1,f+1] clipped
    float a = S[(size_t)f * 196];
    if (f > 0)      a = fmaxf(a, S[(size_t)(f - 1) * 196]);
    if (f + 1 < 64) a = fmaxf(a, S[(size_t)(f + 1) * 196]);
    int f2 = f + 1;  // f<=62 so f2<=63, same video
    float b = fmaxf(S[(size_t)f2 * 196], S[(size_t)(f2 - 1) * 196]);
    if (f2 + 1 < 64) b = fmaxf(b, S[(size_t)(f2 + 1) * 196]);
    feat[(size_t)r * FEATD + col] = 0.5f * (a + b);
}

// ---------------- embedding gather ----------------
__global__ void embed_kernel(const int* __restrict__ txt, const float* __restrict__ emb,
                             float* __restrict__ x0) {
    int idx = blockIdx.x * 256 + threadIdx.x;
    if (idx >= NROW * EDIM) return;
    int e = idx % EDIM, nt = idx / EDIM;
    x0[idx] = emb[(size_t)txt[nt] * EDIM + e];
}

// ---------------- pre-gate GEMM: out[d][m][j] = A[m,:K] . W[d][j][:K] + b1+b2
// 64x64 tile, 256 thr, 4x4 microtile, BK=16
__global__ __launch_bounds__(256) void pregate_kernel(
    const float* __restrict__ A,    // [7680][K]
    const float* __restrict__ W,    // [2][1024][K]
    const float* __restrict__ b1,   // [2][1024]
    const float* __restrict__ b2,   // [2][1024]
    float* __restrict__ out,        // [2][7680][1024]
    int K)
{
    int d  = blockIdx.z;
    int m0 = blockIdx.x * 64;
    int j0 = blockIdx.y * 64;
    const float* Wd = W + (size_t)d * G4 * K;
    float* outd = out + (size_t)d * NROW * G4;
    __shared__ __align__(16) float a_s[16][68];
    __shared__ __align__(16) float b_s[16][68];
    int tid = threadIdx.x;
    int tn = tid & 15, tm = tid >> 4;
    float acc[4][4] = {};
    for (int k0 = 0; k0 < K; k0 += 16) {
#pragma unroll
        for (int li = 0; li < 4; li++) {
            int e = tid + li * 256;
            int mm = e >> 4, kk = e & 15;
            int k = k0 + kk;
            a_s[kk][mm] = (k < K) ? A[(size_t)(m0 + mm) * K + k] : 0.0f;
            b_s[kk][mm] = (k < K) ? Wd[(size_t)(j0 + mm) * K + k] : 0.0f;
        }
        __syncthreads();
#pragma unroll
        for (int kk = 0; kk < 16; kk++) {
            float4 av = *(const float4*)&a_s[kk][tm * 4];
            float4 bv = *(const float4*)&b_s[kk][tn * 4];
#pragma unroll
            for (int mi = 0; mi < 4; mi++) {
                float am = (&av.x)[mi];
#pragma unroll
                for (int ni = 0; ni < 4; ni++)
                    acc[mi][ni] = fmaf(am, (&bv.x)[ni], acc[mi][ni]);
            }
        }
        __syncthreads();
    }
#pragma unroll
    for (int mi = 0; mi < 4; mi++)
#pragma unroll
        for (int ni = 0; ni < 4; ni++) {
            int j = j0 + tn * 4 + ni;
            outd[(size_t)(m0 + tm * 4 + mi) * G4 + j] =
                acc[mi][ni] + b1[d * G4 + j] + b2[d * G4 + j];
        }
}

// ---------------- recurrent LSTM, one layer, both dirs.
// grid (80, 2): 3 batch rows/block; thread = hidden unit, owns gates {hu,256+hu,512+hu,768+hu}
__global__ __launch_bounds__(256) void lstm_kernel(
    const float* __restrict__ pre,    // [2][7680][1024]
    const float* __restrict__ whhTl,  // this layer: [2][256(k)][256(hu)][4(g)]
    const int* __restrict__ lens,     // [240]
    float* __restrict__ hout)         // [7680][512]
{
    int d  = blockIdx.y;
    int n0 = blockIdx.x * 3;
    int hu = threadIdx.x;
    __shared__ __align__(16) float hs[2][3][256];
    float h[3] = {0.f, 0.f, 0.f}, c[3] = {0.f, 0.f, 0.f};
    int len[3] = {lens[n0], lens[n0 + 1], lens[n0 + 2]};
    hs[0][0][hu] = 0.f; hs[0][1][hu] = 0.f; hs[0][2][hu] = 0.f;
    __syncthreads();
    int cur = 0;
    const float* wbase = whhTl + (size_t)d * 262144;
    const float* preb  = pre + (size_t)d * NROW * G4;
    for (int ss = 0; ss < 32; ss++) {
        int t = d ? (31 - ss) : ss;
        float ai[3], af[3], ag[3], ao[3];
#pragma unroll
        for (int b = 0; b < 3; b++) {
            const float* pp = preb + ((size_t)(n0 + b) * TT + t) * G4 + hu;
            ai[b] = pp[0]; af[b] = pp[256]; ag[b] = pp[512]; ao[b] = pp[768];
        }
#pragma unroll 2
        for (int k0 = 0; k0 < 256; k0 += 4) {
            float4 hv0 = *(const float4*)&hs[cur][0][k0];
            float4 hv1 = *(const float4*)&hs[cur][1][k0];
            float4 hv2 = *(const float4*)&hs[cur][2][k0];
#pragma unroll
            for (int kk = 0; kk < 4; kk++) {
                float4 w = *(const float4*)&wbase[(size_t)(k0 + kk) * 1024 + hu * 4];
                float h0 = (&hv0.x)[kk], h1 = (&hv1.x)[kk], h2 = (&hv2.x)[kk];
                ai[0] = fmaf(w.x, h0, ai[0]); ai[1] = fmaf(w.x, h1, ai[1]); ai[2] = fmaf(w.x, h2, ai[2]);
                af[0] = fmaf(w.y, h0, af[0]); af[1] = fmaf(w.y, h1, af[1]); af[2] = fmaf(w.y, h2, af[2]);
                ag[0] = fmaf(w.z, h0, ag[0]); ag[1] = fmaf(w.z, h1, ag[1]); ag[2] = fmaf(w.z, h2, ag[2]);
                ao[0] = fmaf(w.w, h0, ao[0]); ao[1] = fmaf(w.w, h1, ao[1]); ao[2] = fmaf(w.w, h2, ao[2]);
            }
        }
#pragma unroll
        for (int b = 0; b < 3; b++) {
            float iv = 1.f / (1.f + expf(-ai[b]));
            float fv = 1.f / (1.f + expf(-af[b]));
            float gv = tanhf(ag[b]);
            float ov = 1.f / (1.f + expf(-ao[b]));
            float cn = fmaf(fv, c[b], iv * gv);
            float hn = ov * tanhf(cn);
            bool m = t < len[b];
            float outv = m ? hn : 0.f;
            if (m) { c[b] = cn; h[b] = hn; }
            hout[((size_t)(n0 + b) * TT + t) * 512 + d * 256 + hu] = outv;
        }
        int nxt = cur ^ 1;
        hs[nxt][0][hu] = h[0]; hs[nxt][1][hu] = h[1]; hs[nxt][2][hu] = h[2];
        __syncthreads();
        cur = nxt;
    }
}

// ---------------- masked mean over time -> feat rnn cols ----------------
__global__ void rnn_avg_kernel(const float* __restrict__ h1, const int* __restrict__ lens,
                               float* __restrict__ feat) {
    int idx = blockIdx.x * 256 + threadIdx.x;
    if (idx >= NREC * 512) return;
    int n = idx >> 9, cd = idx & 511;
    float s = 0.f;
    for (int t = 0; t < TT; t++) s += h1[((size_t)n * TT + t) * 512 + cd];
    feat[(size_t)n * FEATD + IMGF + cd] = s / (float)lens[n];
}

// ---------------- final linear + sigmoid ----------------
__global__ __launch_bounds__(256) void final_kernel(const float* __restrict__ feat,
                                                    const float* __restrict__ lw,
                                                    const float* __restrict__ lb,
                                                    float* __restrict__ scores) {
    int n = blockIdx.x;
    float acc[NCLS];
#pragma unroll
    for (int cc = 0; cc < NCLS; cc++) acc[cc] = 0.f;
    for (int k = threadIdx.x; k < FEATD; k += 256) {
        float fv = feat[(size_t)n * FEATD + k];
#pragma unroll
        for (int cc = 0; cc < NCLS; cc++)
            acc[cc] = fmaf(fv, lw[cc * FEATD + k], acc[cc]);
    }
#pragma unroll
    for (int cc = 0; cc < NCLS; cc++) {
#pragma unroll
        for (int off = 32; off >= 1; off >>= 1)
            acc[cc] += __shfl_xor(acc[cc], off, 64);
    }
    __shared__ float red[NCLS][4];
    int lane = threadIdx.x & 63, wid = threadIdx.x >> 6;
    if (lane == 0)
        for (int cc = 0; cc < NCLS; cc++) red[cc][wid] = acc[cc];
    __syncthreads();
    if (threadIdx.x < NCLS) {
        float s = red[threadIdx.x][0] + red[threadIdx.x][1] + red[threadIdx.x][2] +
                  red[threadIdx.x][3] + lb[threadIdx.x];
        scores[n * NCLS + threadIdx.x] = 1.f / (1.f + expf(-s));
    }
}

// ---------------- per-video max over 60 records ----------------
__global__ void vidmax_kernel(const float* __restrict__ scores, float* __restrict__ out) {
    int idx = threadIdx.x;
    if (idx < NV * NCLS) {
        int v = idx / NCLS, cc = idx % NCLS;
        float m = -3.0e38f;
        for (int r = 0; r < 60; r++)
            m = fmaxf(m, scores[(v * 60 + r) * NCLS + cc]);
        out[idx] = m;
    }
}

extern "C" void kernel_launch(void* const* d_in, const int* in_sizes, int n_in,
                              void* d_out, int out_size, void* d_ws, size_t ws_size,
                              hipStream_t stream) {
    (void)in_sizes; (void)n_in; (void)out_size; (void)ws_size;
    const float* img  = (const float*)d_in[0];
    const int*   txt  = (const int*)d_in[1];
    const int*   lens = (const int*)d_in[2];
    const float* emb  = (const float*)d_in[7];
    const float* Wih0 = (const float*)d_in[8];
    const float* Whh0 = (const float*)d_in[9];
    const float* bih0 = (const float*)d_in[10];
    const float* bhh0 = (const float*)d_in[11];
    const float* Wih1 = (const float*)d_in[12];
    const float* Whh1 = (const float*)d_in[13];
    const float* bih1 = (const float*)d_in[14];
    const float* bhh1 = (const float*)d_in[15];
    const float* cw   = (const float*)d_in[16];
    const float* cb   = (const float*)d_in[17];
    const float* lw   = (const float*)d_in[18];
    const float* lb   = (const float*)d_in[19];

    float* ws = (float*)d_ws;
    float* wT    = ws;                     // 14112
    float* whhT  = ws + 14112;             // 1,048,576  [l][d][k][hu][g]
    float* x0    = ws + 1062688;           // 2,304,000
    float* pre   = ws + 3366688;           // 15,728,640 (reused both layers)
    float* h0o   = ws + 19095328;          // 3,932,160
    float* h1o   = ws + 23027488;          // 3,932,160
    float* spool = ws + 26959648;          // 1,605,632
    float* feat  = ws + 28565280;          // 1,628,160
    float* scor  = ws + 30193440;          // 4,800   (total 30,198,240 floats ~115 MiB)

    prep_wT_kernel<<<56, 256, 0, stream>>>(cw, wT);
    prep_whhT_kernel<<<4096, 256, 0, stream>>>(Whh0, Whh1, whhT);
    conv_pool_kernel<<<3584, 256, 0, stream>>>(img, wT, cb, spool);
    depth_adj_kernel<<<5880, 256, 0, stream>>>(spool, feat);
    embed_kernel<<<9000, 256, 0, stream>>>(txt, emb, x0);
    pregate_kernel<<<dim3(120, 16, 2), 256, 0, stream>>>(x0, Wih0, bih0, bhh0, pre, EDIM);
    lstm_kernel<<<dim3(80, 2), 256, 0, stream>>>(pre, whhT, lens, h0o);
    pregate_kernel<<<dim3(120, 16, 2), 256, 0, stream>>>(h0o, Wih1, bih1, bhh1, pre, 512);
    lstm_kernel<<<dim3(80, 2), 256, 0, stream>>>(pre, whhT + 524288, lens, h1o);
    rnn_avg_kernel<<<480, 256, 0, stream>>>(h1o, lens, feat);
    final_kernel<<<240, 256, 0, stream>>>(feat, lw, lb, scor);
    vidmax_kernel<<<1, 128, 0, stream>>>(scor, (float*)d_out);
}

// Round 2
// 1985.979 us; speedup vs baseline: 1.4468x; 1.4468x over previous
//
#include <hip/hip_runtime.h>
#include <math.h>

// Problem constants (shapes fixed by setup_inputs)
#define NV 4          // videos
#define FPV 64        // frames per video
#define NREC 240      // text records / kept adjacency pairs
#define TT 32         // text sequence length
#define EDIM 300
#define HID 256
#define G4 1024       // 4*HID
#define OC 32
#define NCLS 20
#define IMGF 6272     // OC*14*14
#define FEATD 6784    // IMGF + 2*HID
#define NROW 7680     // NREC*TT
#define IMG_PIX 50176 // 224*224

typedef __attribute__((ext_vector_type(8))) short short8;
typedef __attribute__((ext_vector_type(16))) float floatx16;

__device__ inline unsigned short f2bf(float x) {
    unsigned int u = __float_as_uint(x);
    unsigned int r = u + 0x7FFFu + ((u >> 16) & 1u);   // RN-even, data has no NaN
    return (unsigned short)(r >> 16);
}
__device__ inline unsigned int pack_bf16(float lo, float hi) {
    return (unsigned int)f2bf(lo) | ((unsigned int)f2bf(hi) << 16);
}

// ---------------- prep: conv weights -> wprep[r=0..63][oc=0..31][q=0..7] bf16
// r = (c*3+kd)*7 + kw (r=63 pad), q = kh (q=7 pad). B[k][oc] for k = r*8+q.
__global__ void prep_wmfma_kernel(const float* __restrict__ cw,
                                  unsigned short* __restrict__ wprep) {
    int idx = blockIdx.x * 256 + threadIdx.x;  // 16384 total
    if (idx >= 64 * 32 * 8) return;
    int q  = idx & 7;
    int oc = (idx >> 3) & 31;
    int r  = idx >> 8;
    float v = 0.f;
    if (r < 63 && q < 7) {
        int pl = r / 7, kw = r % 7;
        int c = pl / 3, kd = pl % 3;
        v = cw[(size_t)oc * 441 + c * 147 + kd * 49 + q * 7 + kw];
    }
    wprep[idx] = f2bf(v);
}

// ---------------- prep: Whh[l][d][j][k] -> whhT[l][d][k][hu][g] ----------
__global__ void prep_whhT_kernel(const float* __restrict__ w0,
                                 const float* __restrict__ w1,
                                 float* __restrict__ whhT) {
    int idx = blockIdx.x * 256 + threadIdx.x;  // < 2^20
    int g  = idx & 3;
    int hu = (idx >> 2) & 255;
    int k  = (idx >> 10) & 255;
    int d  = (idx >> 18) & 1;
    int l  = (idx >> 19) & 1;
    const float* W = l ? w1 : w0;
    whhT[idx] = W[((size_t)d * G4 + (g * 256 + hu)) * 256 + k];
}

// ---------------- conv3d (3x7x7, stride 1,2,2, pad 1,3,3) + 8x8 spatial maxpool
// via implicit-GEMM MFMA 32x32x16 bf16.
// Block = 256 thr (4 waves), handles one (vf, pool row i): loops dy=0..7 over conv
// rows y=8i+dy. Wave w computes pixels x in [32w,32w+32) (x>=112 dead), all 32 oc.
// K = 512: k = r*8 + q; r=(c*3+kd)*7+kw (63 real + 1 pad), q=kh (7 real + 1 pad).
// A[x][k] = in[vf+kd-1][c][2y-3+q][2x-3+kw] staged in LDS column-major:
//   column s = (input col)+4, deinterleaved by parity: region=s&1, u=s>>1,
//   8 q's contiguous (16 B) -> one aligned ds_read_b128 per A fragment.
// Output written as spool[vf][ij=i*14+j][oc] (coalesced over oc).
#define REG_PITCH 1840           // 115 u-slots * 16 B
#define PLANE_PITCH 3680         // 2 regions
#define IN_LDS 33120             // 9 planes
#define WOFF 33120
#define CONV_LDS_TOTAL (33120 + 63 * 512)   // 65376 <= 64 KiB

__global__ __launch_bounds__(256) void conv_pool_kernel(
    const float* __restrict__ img,           // [256][3][224][224]
    const unsigned short* __restrict__ wprep,// [64][32][8] bf16
    const float* __restrict__ cb,            // [32]
    float* __restrict__ spool)               // [256][196][32]
{
    __shared__ __align__(16) unsigned char lds[CONV_LDS_TOTAL];
    int blk = blockIdx.x;          // 3584 = 256 vf * 14 i
    int i  = blk % 14;
    int vf = blk / 14;
    int f  = vf & 63;
    int tid  = threadIdx.x;
    int lane = tid & 63;
    int wv   = tid >> 6;
    int m    = lane & 31;          // A-role: pixel within tile; B/C-role: oc
    int half = lane >> 5;
    int x  = wv * 32 + m;
    int xe = x > 111 ? 111 : x;    // dead lanes clamp (stores masked)

    // stage weights into LDS once (63 r-slots; r=63 handled as zero frag)
    {
        const uint4* wp4 = (const uint4*)wprep;   // first 2016 uint4 = r<63
        uint4* wl4 = (uint4*)(lds + WOFF);
        for (int k0 = tid; k0 < 2016; k0 += 256) wl4[k0] = wp4[k0];
    }

    int js = tid & 3;      // q-pair index (rows 2js, 2js+1 of the 8-row window)
    int sp = tid >> 2;     // column-pair index

    float pmax[4] = {-3.0e38f, -3.0e38f, -3.0e38f, -3.0e38f};

    for (int dy = 0; dy < 8; ++dy) {
        int y = i * 8 + dy;
        __syncthreads();   // prior readers done before overwrite (also covers W copy)
        // ---- stage input window (7 rows x 229 cols x 9 planes, bf16, transposed) ----
        {
            int ra = 2 * y - 3 + 2 * js;
            int rb = ra + 1;
            int rac = ra < 0 ? 0 : (ra > 223 ? 223 : ra);
            int rbc = rb < 0 ? 0 : (rb > 223 ? 223 : rb);
            bool raok = (unsigned)ra < 224u;
            bool rbok = ((unsigned)rb < 224u) && (js < 3);   // q=7 -> zero
#pragma unroll 1
            for (int p = 0; p < 9; ++p) {
                int c = p / 3, kd = p - c * 3;
                int zf = f + kd - 1;
                bool fok = (0 <= zf) && (zf < 64);
                const float* plane = img + ((size_t)(vf + kd - 1) * 3 + c) * IMG_PIX;
                unsigned char* ldp = lds + p * PLANE_PITCH;
#pragma unroll
                for (int sb = 0; sb < 2; ++sb) {
                    int s = sb * 128 + sp * 2;     // even
                    if (s >= 230) continue;
                    int g0 = s - 4, g1 = s - 3;
                    float v00 = 0.f, v01 = 0.f, v10 = 0.f, v11 = 0.f;
                    if (fok) {
                        int g0c = g0 < 0 ? 0 : (g0 > 223 ? 223 : g0);
                        int g1c = g1 < 0 ? 0 : (g1 > 223 ? 223 : g1);
                        bool g0ok = (unsigned)g0 < 224u;
                        bool g1ok = (unsigned)g1 < 224u;
                        const float* r0p = plane + rac * 224;
                        const float* r1p = plane + rbc * 224;
                        float a0 = r0p[g0c], a1 = r0p[g1c];
                        float b0 = r1p[g0c], b1 = r1p[g1c];
                        v00 = (raok && g0ok) ? a0 : 0.f;
                        v01 = (raok && g1ok) ? a1 : 0.f;
                        v10 = (rbok && g0ok) ? b0 : 0.f;
                        v11 = (rbok && g1ok) ? b1 : 0.f;
                    }
                    int u = s >> 1;
                    *(unsigned int*)(ldp + u * 16 + js * 4) = pack_bf16(v00, v10);
                    *(unsigned int*)(ldp + REG_PITCH + u * 16 + js * 4) = pack_bf16(v01, v11);
                }
            }
        }
        __syncthreads();
        // ---- MFMA K-loop: 32 steps, r = 2*kk + half ----
        floatx16 acc = {0,0,0,0,0,0,0,0,0,0,0,0,0,0,0,0};
#pragma unroll
        for (int kk = 0; kk < 32; ++kk) {
            int r = kk * 2 + half;
            int pl = r / 7;                 // folds to per-kk constant select
            int kw = r - pl * 7;
            bool pad = (pl > 8);
            if (pad) { pl = 8; kw = 6; }
            int reg = (kw + 1) & 1;
            int hw  = (kw + 1) >> 1;
            const short8 af = *(const short8*)(lds + pl * PLANE_PITCH + reg * REG_PITCH
                                               + (xe + hw) * 16);
            int rcl = pad ? 0 : r;
            short8 bf = *(const short8*)(lds + WOFF + rcl * 512 + m * 16);
            if (pad) { short8 z = {0,0,0,0,0,0,0,0}; bf = z; }
            acc = __builtin_amdgcn_mfma_f32_32x32x16_bf16(af, bf, acc, 0, 0, 0);
        }
        // ---- pool update: C row = (reg&3)+8*(reg>>2)+4*half -> cell = reg>>2 ----
#pragma unroll
        for (int z = 0; z < 16; ++z)
            pmax[z >> 2] = fmaxf(pmax[z >> 2], acc[z]);
    }
    // combine within-cell x from both halves, add bias, store
#pragma unroll
    for (int rc = 0; rc < 4; ++rc)
        pmax[rc] = fmaxf(pmax[rc], __shfl_xor(pmax[rc], 32, 64));
    if (half == 0) {
        float bias = cb[m];                 // m = oc here
#pragma unroll
        for (int rc = 0; rc < 4; ++rc) {
            int jc = wv * 4 + rc;
            if (jc < 14)
                spool[((size_t)vf * 196 + i * 14 + jc) * 32 + m] = pmax[rc] + bias;
        }
    }
}

// ---------------- depth maxpool (window 3, pad 1) + adjacent-frame avg -> feat
// spool layout: [vf][ij][oc]
__global__ void depth_adj_kernel(const float* __restrict__ spool, float* __restrict__ feat) {
    int idx = blockIdx.x * 256 + threadIdx.x;
    if (idx >= NREC * IMGF) return;
    int col = idx % IMGF;            // o*196 + ij
    int r   = idx / IMGF;
    int o  = col / 196, ij = col % 196;
    int g  = r / 15, jj = r % 15;
    int tt = 16 * g + jj;            // kept adjacency index
    int v  = tt >> 6, f = tt & 63;   // f <= 62
    const int FS = 196 * 32;
    const float* S = spool + ((size_t)(v * 64) * 196 + ij) * 32 + o;
    float a = S[(size_t)f * FS];
    if (f > 0) a = fmaxf(a, S[(size_t)(f - 1) * FS]);
    a = fmaxf(a, S[(size_t)(f + 1) * FS]);          // f+1 <= 63 always
    int f2 = f + 1;
    float b = fmaxf(S[(size_t)f2 * FS], S[(size_t)(f2 - 1) * FS]);
    if (f2 + 1 < 64) b = fmaxf(b, S[(size_t)(f2 + 1) * FS]);
    feat[(size_t)r * FEATD + col] = 0.5f * (a + b);
}

// ---------------- embedding gather ----------------
__global__ void embed_kernel(const int* __restrict__ txt, const float* __restrict__ emb,
                             float* __restrict__ x0) {
    int idx = blockIdx.x * 256 + threadIdx.x;
    if (idx >= NROW * EDIM) return;
    int e = idx % EDIM, nt = idx / EDIM;
    x0[idx] = emb[(size_t)txt[nt] * EDIM + e];
}

// ---------------- pre-gate GEMM: out[d][m][j] = A[m,:K] . W[d][j][:K] + b1+b2
__global__ __launch_bounds__(256) void pregate_kernel(
    const float* __restrict__ A,    // [7680][K]
    const float* __restrict__ W,    // [2][1024][K]
    const float* __restrict__ b1,   // [2][1024]
    const float* __restrict__ b2,   // [2][1024]
    float* __restrict__ out,        // [2][7680][1024]
    int K)
{
    int d  = blockIdx.z;
    int m0 = blockIdx.x * 64;
    int j0 = blockIdx.y * 64;
    const float* Wd = W + (size_t)d * G4 * K;
    float* outd = out + (size_t)d * NROW * G4;
    __shared__ __align__(16) float a_s[16][68];
    __shared__ __align__(16) float b_s[16][68];
    int tid = threadIdx.x;
    int tn = tid & 15, tm = tid >> 4;
    float acc[4][4] = {};
    for (int k0 = 0; k0 < K; k0 += 16) {
#pragma unroll
        for (int li = 0; li < 4; li++) {
            int e = tid + li * 256;
            int mm = e >> 4, kk = e & 15;
            int k = k0 + kk;
            a_s[kk][mm] = (k < K) ? A[(size_t)(m0 + mm) * K + k] : 0.0f;
            b_s[kk][mm] = (k < K) ? Wd[(size_t)(j0 + mm) * K + k] : 0.0f;
        }
        __syncthreads();
#pragma unroll
        for (int kk = 0; kk < 16; kk++) {
            float4 av = *(const float4*)&a_s[kk][tm * 4];
            float4 bv = *(const float4*)&b_s[kk][tn * 4];
#pragma unroll
            for (int mi = 0; mi < 4; mi++) {
                float am = (&av.x)[mi];
#pragma unroll
                for (int ni = 0; ni < 4; ni++)
                    acc[mi][ni] = fmaf(am, (&bv.x)[ni], acc[mi][ni]);
            }
        }
        __syncthreads();
    }
#pragma unroll
    for (int mi = 0; mi < 4; mi++)
#pragma unroll
        for (int ni = 0; ni < 4; ni++) {
            int j = j0 + tn * 4 + ni;
            outd[(size_t)(m0 + tm * 4 + mi) * G4 + j] =
                acc[mi][ni] + b1[d * G4 + j] + b2[d * G4 + j];
        }
}

// ---------------- recurrent LSTM, one layer, both dirs ----------------
__global__ __launch_bounds__(256) void lstm_kernel(
    const float* __restrict__ pre,    // [2][7680][1024]
    const float* __restrict__ whhTl,  // this layer: [2][256(k)][256(hu)][4(g)]
    const int* __restrict__ lens,     // [240]
    float* __restrict__ hout)         // [7680][512]
{
    int d  = blockIdx.y;
    int n0 = blockIdx.x * 3;
    int hu = threadIdx.x;
    __shared__ __align__(16) float hs[2][3][256];
    float h[3] = {0.f, 0.f, 0.f}, c[3] = {0.f, 0.f, 0.f};
    int len[3] = {lens[n0], lens[n0 + 1], lens[n0 + 2]};
    hs[0][0][hu] = 0.f; hs[0][1][hu] = 0.f; hs[0][2][hu] = 0.f;
    __syncthreads();
    int cur = 0;
    const float* wbase = whhTl + (size_t)d * 262144;
    const float* preb  = pre + (size_t)d * NROW * G4;
    for (int ss = 0; ss < 32; ss++) {
        int t = d ? (31 - ss) : ss;
        float ai[3], af[3], ag[3], ao[3];
#pragma unroll
        for (int b = 0; b < 3; b++) {
            const float* pp = preb + ((size_t)(n0 + b) * TT + t) * G4 + hu;
            ai[b] = pp[0]; af[b] = pp[256]; ag[b] = pp[512]; ao[b] = pp[768];
        }
#pragma unroll 2
        for (int k0 = 0; k0 < 256; k0 += 4) {
            float4 hv0 = *(const float4*)&hs[cur][0][k0];
            float4 hv1 = *(const float4*)&hs[cur][1][k0];
            float4 hv2 = *(const float4*)&hs[cur][2][k0];
#pragma unroll
            for (int kk = 0; kk < 4; kk++) {
                float4 w = *(const float4*)&wbase[(size_t)(k0 + kk) * 1024 + hu * 4];
                float h0 = (&hv0.x)[kk], h1 = (&hv1.x)[kk], h2 = (&hv2.x)[kk];
                ai[0] = fmaf(w.x, h0, ai[0]); ai[1] = fmaf(w.x, h1, ai[1]); ai[2] = fmaf(w.x, h2, ai[2]);
                af[0] = fmaf(w.y, h0, af[0]); af[1] = fmaf(w.y, h1, af[1]); af[2] = fmaf(w.y, h2, af[2]);
                ag[0] = fmaf(w.z, h0, ag[0]); ag[1] = fmaf(w.z, h1, ag[1]); ag[2] = fmaf(w.z, h2, ag[2]);
                ao[0] = fmaf(w.w, h0, ao[0]); ao[1] = fmaf(w.w, h1, ao[1]); ao[2] = fmaf(w.w, h2, ao[2]);
            }
        }
#pragma unroll
        for (int b = 0; b < 3; b++) {
            float iv = 1.f / (1.f + expf(-ai[b]));
            float fv = 1.f / (1.f + expf(-af[b]));
            float gv = tanhf(ag[b]);
            float ov = 1.f / (1.f + expf(-ao[b]));
            float cn = fmaf(fv, c[b], iv * gv);
            float hn = ov * tanhf(cn);
            bool mk = t < len[b];
            float outv = mk ? hn : 0.f;
            if (mk) { c[b] = cn; h[b] = hn; }
            hout[((size_t)(n0 + b) * TT + t) * 512 + d * 256 + hu] = outv;
        }
        int nxt = cur ^ 1;
        hs[nxt][0][hu] = h[0]; hs[nxt][1][hu] = h[1]; hs[nxt][2][hu] = h[2];
        __syncthreads();
        cur = nxt;
    }
}

// ---------------- masked mean over time -> feat rnn cols ----------------
__global__ void rnn_avg_kernel(const float* __restrict__ h1, const int* __restrict__ lens,
                               float* __restrict__ feat) {
    int idx = blockIdx.x * 256 + threadIdx.x;
    if (idx >= NREC * 512) return;
    int n = idx >> 9, cd = idx & 511;
    float s = 0.f;
    for (int t = 0; t < TT; t++) s += h1[((size_t)n * TT + t) * 512 + cd];
    feat[(size_t)n * FEATD + IMGF + cd] = s / (float)lens[n];
}

// ---------------- final linear + sigmoid ----------------
__global__ __launch_bounds__(256) void final_kernel(const float* __restrict__ feat,
                                                    const float* __restrict__ lw,
                                                    const float* __restrict__ lb,
                                                    float* __restrict__ scores) {
    int n = blockIdx.x;
    float acc[NCLS];
#pragma unroll
    for (int cc = 0; cc < NCLS; cc++) acc[cc] = 0.f;
    for (int k = threadIdx.x; k < FEATD; k += 256) {
        float fv = feat[(size_t)n * FEATD + k];
#pragma unroll
        for (int cc = 0; cc < NCLS; cc++)
            acc[cc] = fmaf(fv, lw[cc * FEATD + k], acc[cc]);
    }
#pragma unroll
    for (int cc = 0; cc < NCLS; cc++) {
#pragma unroll
        for (int off = 32; off >= 1; off >>= 1)
            acc[cc] += __shfl_xor(acc[cc], off, 64);
    }
    __shared__ float red[NCLS][4];
    int lane = threadIdx.x & 63, wid = threadIdx.x >> 6;
    if (lane == 0)
        for (int cc = 0; cc < NCLS; cc++) red[cc][wid] = acc[cc];
    __syncthreads();
    if (threadIdx.x < NCLS) {
        float s = red[threadIdx.x][0] + red[threadIdx.x][1] + red[threadIdx.x][2] +
                  red[threadIdx.x][3] + lb[threadIdx.x];
        scores[n * NCLS + threadIdx.x] = 1.f / (1.f + expf(-s));
    }
}

// ---------------- per-video max over 60 records ----------------
__global__ void vidmax_kernel(const float* __restrict__ scores, float* __restrict__ out) {
    int idx = threadIdx.x;
    if (idx < NV * NCLS) {
        int v = idx / NCLS, cc = idx % NCLS;
        float m = -3.0e38f;
        for (int r = 0; r < 60; r++)
            m = fmaxf(m, scores[(v * 60 + r) * NCLS + cc]);
        out[idx] = m;
    }
}

extern "C" void kernel_launch(void* const* d_in, const int* in_sizes, int n_in,
                              void* d_out, int out_size, void* d_ws, size_t ws_size,
                              hipStream_t stream) {
    (void)in_sizes; (void)n_in; (void)out_size; (void)ws_size;
    const float* img  = (const float*)d_in[0];
    const int*   txt  = (const int*)d_in[1];
    const int*   lens = (const int*)d_in[2];
    const float* emb  = (const float*)d_in[7];
    const float* Wih0 = (const float*)d_in[8];
    const float* Whh0 = (const float*)d_in[9];
    const float* bih0 = (const float*)d_in[10];
    const float* bhh0 = (const float*)d_in[11];
    const float* Wih1 = (const float*)d_in[12];
    const float* Whh1 = (const float*)d_in[13];
    const float* bih1 = (const float*)d_in[14];
    const float* bhh1 = (const float*)d_in[15];
    const float* cw   = (const float*)d_in[16];
    const float* cb   = (const float*)d_in[17];
    const float* lw   = (const float*)d_in[18];
    const float* lb   = (const float*)d_in[19];

    float* ws = (float*)d_ws;
    unsigned short* wprep = (unsigned short*)ws;  // 16384 ushort = 8192 floats (< 14112 slot)
    float* whhT  = ws + 14112;             // 1,048,576  [l][d][k][hu][g]
    float* x0    = ws + 1062688;           // 2,304,000
    float* pre   = ws + 3366688;           // 15,728,640 (reused both layers)
    float* h0o   = ws + 19095328;          // 3,932,160
    float* h1o   = ws + 23027488;          // 3,932,160
    float* spool = ws + 26959648;          // 1,605,632  [256 vf][196 ij][32 oc]
    float* feat  = ws + 28565280;          // 1,628,160
    float* scor  = ws + 30193440;          // 4,800

    prep_wmfma_kernel<<<64, 256, 0, stream>>>(cw, wprep);
    prep_whhT_kernel<<<4096, 256, 0, stream>>>(Whh0, Whh1, whhT);
    conv_pool_kernel<<<3584, 256, 0, stream>>>(img, wprep, cb, spool);
    depth_adj_kernel<<<5880, 256, 0, stream>>>(spool, feat);
    embed_kernel<<<9000, 256, 0, stream>>>(txt, emb, x0);
    pregate_kernel<<<dim3(120, 16, 2), 256, 0, stream>>>(x0, Wih0, bih0, bhh0, pre, EDIM);
    lstm_kernel<<<dim3(80, 2), 256, 0, stream>>>(pre, whhT, lens, h0o);
    pregate_kernel<<<dim3(120, 16, 2), 256, 0, stream>>>(h0o, Wih1, bih1, bhh1, pre, 512);
    lstm_kernel<<<dim3(80, 2), 256, 0, stream>>>(pre, whhT + 524288, lens, h1o);
    rnn_avg_kernel<<<480, 256, 0, stream>>>(h1o, lens, feat);
    final_kernel<<<240, 256, 0, stream>>>(feat, lw, lb, scor);
    vidmax_kernel<<<1, 128, 0, stream>>>(scor, (float*)d_out);
}

// Round 4
// 1159.147 us; speedup vs baseline: 2.4789x; 1.7133x over previous
//
#include <hip/hip_runtime.h>
#include <math.h>

// Problem constants (shapes fixed by setup_inputs)
#define NV 4
#define NREC 240
#define TT 32
#define EDIM 300
#define HID 256
#define G4 1024
#define OC 32
#define NCLS 20
#define IMGF 6272     // OC*14*14
#define FEATD 6784
#define NROW 7680
#define IMG_PIX 50176

typedef __attribute__((ext_vector_type(8))) short short8;
typedef __attribute__((ext_vector_type(16))) float floatx16;
typedef __attribute__((ext_vector_type(2))) _Float16 h2;
typedef unsigned short u16;

__device__ inline u16 f2bf(float x) {
    unsigned int u = __float_as_uint(x);
    unsigned int r = u + 0x7FFFu + ((u >> 16) & 1u);
    return (u16)(r >> 16);
}

// ---------------- prep: conv weights -> wprep[r=0..63][oc=0..31][q=kh 0..7] bf16
__global__ void prep_wmfma_kernel(const float* __restrict__ cw, u16* __restrict__ wprep) {
    int idx = blockIdx.x * 256 + threadIdx.x;
    if (idx >= 64 * 32 * 8) return;
    int q  = idx & 7;
    int oc = (idx >> 3) & 31;
    int r  = idx >> 8;
    float v = 0.f;
    if (r < 63 && q < 7) {
        int pl = r / 7, kw = r % 7;
        int c = pl / 3, kd = pl % 3;
        v = cw[(size_t)oc * 441 + c * 147 + kd * 49 + q * 7 + kw];
    }
    wprep[idx] = f2bf(v);
}

// ---------------- prep: Whh fp32 -> whhH[l][d][k2][hu][g][p] fp16 ----------
__global__ void prep_whhH_kernel(const float* __restrict__ w0, const float* __restrict__ w1,
                                 _Float16* __restrict__ whhH) {
    int idx = blockIdx.x * 256 + threadIdx.x;   // 2^20
    int p  = idx & 1;
    int g  = (idx >> 1) & 3;
    int hu = (idx >> 3) & 255;
    int k2 = (idx >> 11) & 127;
    int d  = (idx >> 18) & 1;
    int l  = (idx >> 19) & 1;
    const float* W = l ? w1 : w0;
    whhH[idx] = (_Float16)W[((size_t)d * G4 + g * 256 + hu) * 256 + k2 * 2 + p];
}

// ---------------- prep: Wih fp32 [2][1024][K] -> bf16 [2][1024][Kp] ----------
__global__ void prep_wihb_kernel(const float* __restrict__ src, u16* __restrict__ dst,
                                 int K, int Kp) {
    int idx = blockIdx.x * 256 + threadIdx.x;
    if (idx >= 2 * 1024 * Kp) return;
    int k = idx % Kp;
    int j = idx / Kp;
    dst[idx] = (k < K) ? f2bf(src[(size_t)j * K + k]) : (u16)0;
}

// ---------------- conv3d + 8x8 spatial maxpool, rolling-window implicit MFMA GEMM
#define REG_PITCH 1840
#define PLANE_PITCH 3680
#define WOFF 33120
#define CONV_LDS_TOTAL (33120 + 63 * 512)   // 65376

template<int RL>
__device__ __attribute__((always_inline))
static void conv_mfma_pass(const unsigned char* lds, int xe, int half, int m, floatx16& acc) {
#pragma unroll
    for (int kk = 0; kk < 32; ++kk) {
        int r = kk * 2 + half;
        int pl = r / 7;
        int kw = r - pl * 7;
        bool pad = (pl > 8);
        if (pad) { pl = 8; kw = 6; }
        int reg = (kw + 1) & 1;
        int hw  = (kw + 1) >> 1;
        short8 af = *(const short8*)(lds + pl * PLANE_PITCH + reg * REG_PITCH + (xe + hw) * 16);
        int rcl = pad ? 0 : r;
        short8 canon = *(const short8*)(lds + WOFF + rcl * 512 + m * 16);
        if (pad) { short8 z = {0,0,0,0,0,0,0,0}; canon = z; }
        short8 bfr = __builtin_shufflevector(canon, canon,
            (RL)&7, (RL+1)&7, (RL+2)&7, (RL+3)&7, (RL+4)&7, (RL+5)&7, (RL+6)&7, (RL+7)&7);
        acc = __builtin_amdgcn_mfma_f32_32x32x16_bf16(af, bfr, acc, 0, 0, 0);
    }
}

__global__ __launch_bounds__(256) void conv_pool_kernel(
    const float* __restrict__ img,   // [256][3][224][224]
    const u16* __restrict__ wprep,   // [64][32][8] bf16
    const float* __restrict__ cb,
    float* __restrict__ spool)       // [256][196][32]
{
    __shared__ __align__(16) unsigned char lds[CONV_LDS_TOTAL];
    int blk = blockIdx.x;            // 512 = 256 vf * 2 halves
    int hh = blk & 1;
    int vf = blk >> 1;
    int f  = vf & 63;
    int tid  = threadIdx.x;
    int lane = tid & 63;
    int wv   = tid >> 6;
    int m    = lane & 31;
    int half = lane >> 5;
    int x  = wv * 32 + m;
    int xe = x > 111 ? 111 : x;

    // weights -> LDS (63 r-slots)
    {
        const uint4* wp4 = (const uint4*)wprep;
        uint4* wl4 = (uint4*)(lds + WOFF);
        for (int k0 = tid; k0 < 2016; k0 += 256) wl4[k0] = wp4[k0];
    }

    int u = tid & 127;               // staging column (valid < 115)
    int rowsel = tid >> 7;
    int y0 = 56 * hh;

    // ---- initial prime: rows 2y0-3 .. 2y0+3 real, slot of 2y0+4 zeroed ----
    for (int rnd = 0; rnd < 4; ++rnd) {
        int zz = 2 * y0 - 3 + 2 * rnd + rowsel;
        bool force0 = (2 * rnd + rowsel) == 7;
        int zc = zz < 0 ? 0 : (zz > 223 ? 223 : zz);
        bool zok = ((unsigned)zz < 224u) && !force0;
        int col = 2 * u - 4;
        int colc = col < 0 ? 0 : (col > 222 ? 222 : col);
        bool uok = (u >= 2 && u <= 113);
        if (u < 115) {
            int slot = (zz + 16) & 7;
#pragma unroll 1
            for (int p = 0; p < 9; ++p) {
                int c = p / 3, kd = p - c * 3;
                int zf = f + kd - 1;
                int zp = vf + kd - 1;                       // frame plane, may be -1/256
                int zpc = zp < 0 ? 0 : (zp > 255 ? 255 : zp); // CLAMPED: address always in-bounds
                bool ok = zok && uok && (0 <= zf) && (zf < 64);
                float2 pv = *(const float2*)(img + ((size_t)zpc * 3 + c) * IMG_PIX
                                             + (size_t)zc * 224 + colc);
                float vx = ok ? pv.x : 0.f, vy = ok ? pv.y : 0.f;
                unsigned char* ldp = lds + p * PLANE_PITCH;
                *(u16*)(ldp + u * 16 + slot * 2) = f2bf(vx);
                *(u16*)(ldp + REG_PITCH + u * 16 + slot * 2) = f2bf(vy);
            }
        }
    }
    __syncthreads();

    float pmax[4];
    for (int y = y0; y < y0 + 56; ++y) {
        int dy = y & 7;
        if (dy == 0) {
#pragma unroll
            for (int rc = 0; rc < 4; ++rc) pmax[rc] = -3.0e38f;
        }
        // ---- prefetch next 2 rows into registers (z = 2y+4, 2y+5) ----
        int zz = 2 * y + 4 + rowsel;
        int zc = zz > 223 ? 223 : zz;
        bool zok = zz <= 223;
        int col = 2 * u - 4;
        int colc = col < 0 ? 0 : (col > 222 ? 222 : col);
        bool uok = (u >= 2 && u <= 113);
        float2 pf[9];
#pragma unroll
        for (int p = 0; p < 9; ++p) {
            int c = p / 3, kd = p - c * 3;
            int zp = vf + kd - 1;
            int zpc = zp < 0 ? 0 : (zp > 255 ? 255 : zp);   // CLAMPED
            pf[p] = *(const float2*)(img + ((size_t)zpc * 3 + c) * IMG_PIX
                                     + (size_t)zc * 224 + colc);
        }
        // ---- MFMA pass with y-dependent B rotation ----
        floatx16 acc = {0,0,0,0,0,0,0,0,0,0,0,0,0,0,0,0};
        switch (y & 3) {
            case 0: conv_mfma_pass<3>(lds, xe, half, m, acc); break;
            case 1: conv_mfma_pass<1>(lds, xe, half, m, acc); break;
            case 2: conv_mfma_pass<7>(lds, xe, half, m, acc); break;
            default: conv_mfma_pass<5>(lds, xe, half, m, acc); break;
        }
#pragma unroll
        for (int z = 0; z < 16; ++z)
            pmax[z >> 2] = fmaxf(pmax[z >> 2], acc[z]);
        if (dy == 7) {
#pragma unroll
            for (int rc = 0; rc < 4; ++rc)
                pmax[rc] = fmaxf(pmax[rc], __shfl_xor(pmax[rc], 32, 64));
            if (half == 0) {
                float bias = cb[m];
                int i = y >> 3;
#pragma unroll
                for (int rc = 0; rc < 4; ++rc) {
                    int jc = wv * 4 + rc;
                    if (jc < 14)
                        spool[((size_t)vf * 196 + i * 14 + jc) * 32 + m] = pmax[rc] + bias;
                }
            }
        }
        __syncthreads();
        // ---- commit staged rows ----
        if (u < 115) {
            int slot = (zz + 16) & 7;
#pragma unroll 1
            for (int p = 0; p < 9; ++p) {
                int c = p / 3, kd = p - c * 3;
                int zf = f + kd - 1;
                bool ok = zok && uok && (0 <= zf) && (zf < 64);
                float vx = ok ? pf[p].x : 0.f, vy = ok ? pf[p].y : 0.f;
                unsigned char* ldp = lds + p * PLANE_PITCH;
                *(u16*)(ldp + u * 16 + slot * 2) = f2bf(vx);
                *(u16*)(ldp + REG_PITCH + u * 16 + slot * 2) = f2bf(vy);
            }
        }
        __syncthreads();
    }
}

// ---------------- depth maxpool + adjacent-frame avg -> feat image cols ----------------
__global__ void depth_adj_kernel(const float* __restrict__ spool, float* __restrict__ feat) {
    int idx = blockIdx.x * 256 + threadIdx.x;
    if (idx >= NREC * IMGF) return;
    int col = idx % IMGF;
    int r   = idx / IMGF;
    int o  = col / 196, ij = col % 196;
    int g  = r / 15, jj = r % 15;
    int tt = 16 * g + jj;
    int v  = tt >> 6, f = tt & 63;
    const int FS = 196 * 32;
    const float* S = spool + ((size_t)(v * 64) * 196 + ij) * 32 + o;
    float a = S[(size_t)f * FS];
    if (f > 0) a = fmaxf(a, S[(size_t)(f - 1) * FS]);
    a = fmaxf(a, S[(size_t)(f + 1) * FS]);
    int f2 = f + 1;
    float b = fmaxf(S[(size_t)f2 * FS], S[(size_t)(f2 - 1) * FS]);
    if (f2 + 1 < 64) b = fmaxf(b, S[(size_t)(f2 + 1) * FS]);
    feat[(size_t)r * FEATD + col] = 0.5f * (a + b);
}

// ---------------- embedding gather -> bf16 [7680][320] (zero-padded) ----------------
__global__ void embed_bf_kernel(const int* __restrict__ txt, const float* __restrict__ emb,
                                u16* __restrict__ x0b) {
    int idx = blockIdx.x * 256 + threadIdx.x;
    if (idx >= NROW * 320) return;
    int e = idx % 320, nt = idx / 320;
    x0b[idx] = (e < EDIM) ? f2bf(emb[(size_t)txt[nt] * EDIM + e]) : (u16)0;
}

// ---------------- pre-gate GEMM via MFMA: out[d][m][j] = A[m,:].W[d][j,:] + b1+b2
#define PGP 40   // LDS row pitch in shorts (80 B)
__global__ __launch_bounds__(256) void pregate_mfma(
    const u16* __restrict__ A,    // [7680][Kp] bf16
    const u16* __restrict__ W,    // [2][1024][Kp] bf16
    const float* __restrict__ b1, const float* __restrict__ b2,
    float* __restrict__ out, int Kp)
{
    __shared__ __align__(16) u16 a_s[128 * PGP];
    __shared__ __align__(16) u16 b_s[128 * PGP];
    int d  = blockIdx.z;
    int m0 = blockIdx.x * 128;
    int j0 = blockIdx.y * 128;
    const u16* Wd = W + (size_t)d * G4 * Kp;
    float* outd = out + (size_t)d * NROW * G4;
    int tid = threadIdx.x;
    int lane = tid & 63;
    int wv = tid >> 6;
    int wm = wv & 1, wn = wv >> 1;
    int ln31 = lane & 31, lh = lane >> 5;
    floatx16 acc[2][2];
#pragma unroll
    for (int a = 0; a < 2; a++)
#pragma unroll
        for (int b = 0; b < 2; b++) {
            floatx16 z = {0,0,0,0,0,0,0,0,0,0,0,0,0,0,0,0};
            acc[a][b] = z;
        }
    for (int k0 = 0; k0 < Kp; k0 += 32) {
#pragma unroll
        for (int li = 0; li < 2; li++) {
            int e = tid + li * 256;
            int row = e >> 2, part = e & 3;
            uint4 va = *(const uint4*)(A + (size_t)(m0 + row) * Kp + k0 + part * 8);
            *(uint4*)&a_s[row * PGP + part * 8] = va;
            uint4 vb = *(const uint4*)(Wd + (size_t)(j0 + row) * Kp + k0 + part * 8);
            *(uint4*)&b_s[row * PGP + part * 8] = vb;
        }
        __syncthreads();
#pragma unroll
        for (int kk = 0; kk < 2; kk++) {
            int ko = kk * 16 + lh * 8;
            short8 a0 = *(const short8*)&a_s[(wm * 64 + ln31) * PGP + ko];
            short8 a1 = *(const short8*)&a_s[(wm * 64 + 32 + ln31) * PGP + ko];
            short8 b0 = *(const short8*)&b_s[(wn * 64 + ln31) * PGP + ko];
            short8 b1v = *(const short8*)&b_s[(wn * 64 + 32 + ln31) * PGP + ko];
            acc[0][0] = __builtin_amdgcn_mfma_f32_32x32x16_bf16(a0, b0, acc[0][0], 0, 0, 0);
            acc[0][1] = __builtin_amdgcn_mfma_f32_32x32x16_bf16(a0, b1v, acc[0][1], 0, 0, 0);
            acc[1][0] = __builtin_amdgcn_mfma_f32_32x32x16_bf16(a1, b0, acc[1][0], 0, 0, 0);
            acc[1][1] = __builtin_amdgcn_mfma_f32_32x32x16_bf16(a1, b1v, acc[1][1], 0, 0, 0);
        }
        __syncthreads();
    }
#pragma unroll
    for (int mi = 0; mi < 2; mi++)
#pragma unroll
        for (int ni = 0; ni < 2; ni++) {
#pragma unroll
            for (int rg = 0; rg < 16; rg++) {
                int row = m0 + wm * 64 + mi * 32 + (rg & 3) + 8 * (rg >> 2) + 4 * lh;
                int colj = j0 + wn * 64 + ni * 32 + ln31;
                outd[(size_t)row * G4 + colj] =
                    acc[mi][ni][rg] + b1[d * G4 + colj] + b2[d * G4 + colj];
            }
        }
}

// ---------------- recurrent LSTM (fp16 weights + dot2), one layer, both dirs ----------
__global__ __launch_bounds__(256) void lstm_kernel(
    const float* __restrict__ pre,     // [2][7680][1024] fp32
    const _Float16* __restrict__ whh,  // [2 d][128 k2][256 hu][4 g][2] fp16
    const int* __restrict__ lens,
    float* __restrict__ houtf,         // [7680][512] fp32 (if !obf)
    u16* __restrict__ houtb,           // [7680][512] bf16 (if obf)
    int obf)
{
    int d  = blockIdx.y;
    int n0 = blockIdx.x * 3;
    int hu = threadIdx.x;
    __shared__ __align__(16) _Float16 hs[2][3][256];
    float h[3] = {0.f, 0.f, 0.f}, c[3] = {0.f, 0.f, 0.f};
    int len[3] = {lens[n0], lens[n0 + 1], lens[n0 + 2]};
    hs[0][0][hu] = (_Float16)0.f; hs[0][1][hu] = (_Float16)0.f; hs[0][2][hu] = (_Float16)0.f;
    __syncthreads();
    int cur = 0;
    const _Float16* wb = whh + (size_t)d * 262144;
    const float* preb = pre + (size_t)d * NROW * G4;
    for (int ss = 0; ss < 32; ss++) {
        int t = d ? (31 - ss) : ss;
        float ai[3], af[3], ag[3], ao[3];
#pragma unroll
        for (int b = 0; b < 3; b++) {
            const float* pp = preb + ((size_t)(n0 + b) * TT + t) * G4 + hu;
            ai[b] = pp[0]; af[b] = pp[256]; ag[b] = pp[512]; ao[b] = pp[768];
        }
#pragma unroll 4
        for (int k2 = 0; k2 < 128; k2++) {
            uint4 wr = *(const uint4*)(wb + ((size_t)k2 * 256 + hu) * 8);
            h2 wi = __builtin_bit_cast(h2, wr.x);
            h2 wf = __builtin_bit_cast(h2, wr.y);
            h2 wg = __builtin_bit_cast(h2, wr.z);
            h2 wo = __builtin_bit_cast(h2, wr.w);
#pragma unroll
            for (int b = 0; b < 3; b++) {
                h2 hv = *(const h2*)&hs[cur][b][2 * k2];
#if __has_builtin(__builtin_amdgcn_fdot2)
                ai[b] = __builtin_amdgcn_fdot2(wi, hv, ai[b], false);
                af[b] = __builtin_amdgcn_fdot2(wf, hv, af[b], false);
                ag[b] = __builtin_amdgcn_fdot2(wg, hv, ag[b], false);
                ao[b] = __builtin_amdgcn_fdot2(wo, hv, ao[b], false);
#else
                ai[b] += (float)wi.x * (float)hv.x + (float)wi.y * (float)hv.y;
                af[b] += (float)wf.x * (float)hv.x + (float)wf.y * (float)hv.y;
                ag[b] += (float)wg.x * (float)hv.x + (float)wg.y * (float)hv.y;
                ao[b] += (float)wo.x * (float)hv.x + (float)wo.y * (float)hv.y;
#endif
            }
        }
        int nxt = cur ^ 1;
#pragma unroll
        for (int b = 0; b < 3; b++) {
            float iv = 1.f / (1.f + expf(-ai[b]));
            float fv = 1.f / (1.f + expf(-af[b]));
            float gv = tanhf(ag[b]);
            float ov = 1.f / (1.f + expf(-ao[b]));
            float cn = fmaf(fv, c[b], iv * gv);
            float hn = ov * tanhf(cn);
            bool mk = t < len[b];
            float outv = mk ? hn : 0.f;
            if (mk) { c[b] = cn; h[b] = hn; }
            size_t oidx = ((size_t)(n0 + b) * TT + t) * 512 + d * 256 + hu;
            if (obf) houtb[oidx] = f2bf(outv);
            else     houtf[oidx] = outv;
            hs[nxt][b][hu] = (_Float16)h[b];
        }
        __syncthreads();
        cur = nxt;
    }
}

// ---------------- masked mean over time -> feat rnn cols ----------------
__global__ void rnn_avg_kernel(const float* __restrict__ h1, const int* __restrict__ lens,
                               float* __restrict__ feat) {
    int idx = blockIdx.x * 256 + threadIdx.x;
    if (idx >= NREC * 512) return;
    int n = idx >> 9, cd = idx & 511;
    float s = 0.f;
    for (int t = 0; t < TT; t++) s += h1[((size_t)n * TT + t) * 512 + cd];
    feat[(size_t)n * FEATD + IMGF + cd] = s / (float)lens[n];
}

// ---------------- final linear + sigmoid ----------------
__global__ __launch_bounds__(256) void final_kernel(const float* __restrict__ feat,
                                                    const float* __restrict__ lw,
                                                    const float* __restrict__ lb,
                                                    float* __restrict__ scores) {
    int n = blockIdx.x;
    float acc[NCLS];
#pragma unroll
    for (int cc = 0; cc < NCLS; cc++) acc[cc] = 0.f;
    for (int k = threadIdx.x; k < FEATD; k += 256) {
        float fv = feat[(size_t)n * FEATD + k];
#pragma unroll
        for (int cc = 0; cc < NCLS; cc++)
            acc[cc] = fmaf(fv, lw[cc * FEATD + k], acc[cc]);
    }
#pragma unroll
    for (int cc = 0; cc < NCLS; cc++) {
#pragma unroll
        for (int off = 32; off >= 1; off >>= 1)
            acc[cc] += __shfl_xor(acc[cc], off, 64);
    }
    __shared__ float red[NCLS][4];
    int lane = threadIdx.x & 63, wid = threadIdx.x >> 6;
    if (lane == 0)
        for (int cc = 0; cc < NCLS; cc++) red[cc][wid] = acc[cc];
    __syncthreads();
    if (threadIdx.x < NCLS) {
        float s = red[threadIdx.x][0] + red[threadIdx.x][1] + red[threadIdx.x][2] +
                  red[threadIdx.x][3] + lb[threadIdx.x];
        scores[n * NCLS + threadIdx.x] = 1.f / (1.f + expf(-s));
    }
}

// ---------------- per-video max over 60 records ----------------
__global__ void vidmax_kernel(const float* __restrict__ scores, float* __restrict__ out) {
    int idx = threadIdx.x;
    if (idx < NV * NCLS) {
        int v = idx / NCLS, cc = idx % NCLS;
        float m = -3.0e38f;
        for (int r = 0; r < 60; r++)
            m = fmaxf(m, scores[(v * 60 + r) * NCLS + cc]);
        out[idx] = m;
    }
}

extern "C" void kernel_launch(void* const* d_in, const int* in_sizes, int n_in,
                              void* d_out, int out_size, void* d_ws, size_t ws_size,
                              hipStream_t stream) {
    (void)in_sizes; (void)n_in; (void)out_size; (void)ws_size;
    const float* img  = (const float*)d_in[0];
    const int*   txt  = (const int*)d_in[1];
    const int*   lens = (const int*)d_in[2];
    const float* emb  = (const float*)d_in[7];
    const float* Wih0 = (const float*)d_in[8];
    const float* Whh0 = (const float*)d_in[9];
    const float* bih0 = (const float*)d_in[10];
    const float* bhh0 = (const float*)d_in[11];
    const float* Wih1 = (const float*)d_in[12];
    const float* Whh1 = (const float*)d_in[13];
    const float* bih1 = (const float*)d_in[14];
    const float* bhh1 = (const float*)d_in[15];
    const float* cw   = (const float*)d_in[16];
    const float* cb   = (const float*)d_in[17];
    const float* lw   = (const float*)d_in[18];
    const float* lb   = (const float*)d_in[19];

    char* wsb = (char*)d_ws;
    u16*      wprep = (u16*)wsb;                        // 32768 B
    _Float16* whhH  = (_Float16*)(wsb + 32768);         // 2,097,152 B
    u16*      wihb0 = (u16*)(wsb + 2129920);            // 1,310,720 B  [2][1024][320]
    u16*      wihb1 = (u16*)(wsb + 3440640);            // 2,097,152 B  [2][1024][512]
    u16*      x0b   = (u16*)(wsb + 5537792);            // 4,915,200 B  [7680][320]
    float*    pre   = (float*)(wsb + 10452992);         // 62,914,560 B [2][7680][1024]
    u16*      h0b   = (u16*)(wsb + 73367552);           // 7,864,320 B  [7680][512]
    float*    h1o   = (float*)(wsb + 81231872);         // 15,728,640 B
    float*    spool = (float*)(wsb + 96960512);         // 6,422,528 B  [256][196][32]
    float*    feat  = (float*)(wsb + 103383040);        // 6,512,640 B
    float*    scor  = (float*)(wsb + 109895680);        // 19,200 B

    prep_wmfma_kernel<<<64, 256, 0, stream>>>(cw, wprep);
    prep_whhH_kernel<<<4096, 256, 0, stream>>>(Whh0, Whh1, whhH);
    prep_wihb_kernel<<<2560, 256, 0, stream>>>(Wih0, wihb0, 300, 320);
    prep_wihb_kernel<<<4096, 256, 0, stream>>>(Wih1, wihb1, 512, 512);
    conv_pool_kernel<<<512, 256, 0, stream>>>(img, wprep, cb, spool);
    depth_adj_kernel<<<5880, 256, 0, stream>>>(spool, feat);
    embed_bf_kernel<<<9600, 256, 0, stream>>>(txt, emb, x0b);
    pregate_mfma<<<dim3(60, 8, 2), 256, 0, stream>>>(x0b, wihb0, bih0, bhh0, pre, 320);
    lstm_kernel<<<dim3(80, 2), 256, 0, stream>>>(pre, whhH, lens, h1o, h0b, 1);
    pregate_mfma<<<dim3(60, 8, 2), 256, 0, stream>>>(h0b, wihb1, bih1, bhh1, pre, 512);
    lstm_kernel<<<dim3(80, 2), 256, 0, stream>>>(pre, whhH + 524288, lens, h1o, h0b, 0);
    rnn_avg_kernel<<<480, 256, 0, stream>>>(h1o, lens, feat);
    final_kernel<<<240, 256, 0, stream>>>(feat, lw, lb, scor);
    vidmax_kernel<<<1, 128, 0, stream>>>(scor, (float*)d_out);
}